// Round 6
// baseline (242.727 us; speedup 1.0000x reference)
//
#include <hip/hip_runtime.h>

#define BB 64
#define CC 64
#define TT 4000

#define SLABS 8
#define SLABT 500            // t per block
#define NWG   (BB * SLABS)   // 512 blocks = exactly 2/CU on 256 CUs (co-resident)
#define XS_PITCH 520         // shorts per xs row: 512 t-pad + 8 pad; 1040 B, 16B-aligned
#define APITCH 72            // shorts per al row

// ws layout (floats): G_part[8][64][64][64] | S_part[8][64][64] | barrier counter
#define GPART_ELEMS ((size_t)SLABS * BB * CC * CC)
#define SPART_ELEMS ((size_t)SLABS * BB * CC)

typedef short short8 __attribute__((ext_vector_type(8)));
typedef float f32x16 __attribute__((ext_vector_type(16)));

__device__ __forceinline__ short f2bf(float f) {
    unsigned u = __float_as_uint(f);
    u = (u + 0x7FFFu + ((u >> 16) & 1u)) >> 16;   // round-to-nearest-even
    return (short)u;
}
// packed RNE f32x2 -> bf16x2 (lo = a, hi = b)
__device__ __forceinline__ unsigned cvt_pk(float a, float b) {
    unsigned r;
    asm("v_cvt_pk_bf16_f32 %0, %1, %2" : "=v"(r) : "v"(a), "v"(b));
    return r;
}
__device__ __forceinline__ float bfpair(unsigned u) {   // sum of 2 packed bf16
    return __uint_as_float(u << 16) + __uint_as_float(u & 0xFFFF0000u);
}
__device__ __forceinline__ float bf2f(short s) {
    return __uint_as_float(((unsigned)(unsigned short)s) << 16);
}

// One block per (b, slab). b = blockIdx&63 so all 8 slabs of a batch land on the
// same XCD (round-robin) -> phase-2 G_part reads are same-XCD L2 hits.
// Phase 1: stage x[b][:, slab] ONCE as bf16 into LDS; gram partial -> G/S_part.
// Spin grid barrier (512 blocks co-resident by construction).
// Phase 2: redundant per-block softmax (register slab-reduce, no Es LDS) -> al.
// Phase 3: apply out = gamma*P^T x + x entirely from the RESIDENT xs tile --
// no second global read of x, no barriers.
__global__ __launch_bounds__(256, 2)
void fused_attn(const float* __restrict__ x,
                const float* __restrict__ w1, const float* __restrict__ b1,
                const float* __restrict__ w2, const float* __restrict__ b2,
                const float* __restrict__ gamma,
                float* __restrict__ G_part, float* __restrict__ S_part,
                unsigned* __restrict__ bar, float* __restrict__ out) {
    __shared__ short xs[CC * XS_PITCH];   // 66560 B bf16 x tile (lives all phases)
    __shared__ short al[CC * APITCH];     // 9216 B  al[X][Y] = P[Y][X] (bf16)
    __shared__ float red[3 * 256];        // 3072 B  reductions (reused)
    __shared__ float Sb[64];              // 79.1 KB total -> 2 blocks/CU

    const int tid  = threadIdx.x;
    const int lane = tid & 63, wave = tid >> 6;
    const int b    = blockIdx.x & 63;
    const int slab = blockIdx.x >> 6;
    const int t0s  = slab * SLABT;
    const float* xb = x + (size_t)b * CC * TT;
    const int m = lane & 31, half = lane >> 5;
    const int r0 = (wave >> 1) * 32, c0w = (wave & 1) * 32;

    // ---- phase 1a: stage 64 x 500 fp32 -> bf16 (chunk-XOR swizzle, zero pad) ----
    #pragma unroll
    for (int g = 0; g < 4; ++g) {
        float4 v[8];
        #pragma unroll
        for (int k = 0; k < 8; ++k) {
            const int i = tid + 256 * (g * 8 + k);
            const int row = i >> 7, tq = i & 127;          // t = 4*tq
            float4 w = make_float4(0.f, 0.f, 0.f, 0.f);
            if (tq < 125) w = *(const float4*)(xb + row * TT + t0s + 4 * tq);
            v[k] = w;
        }
        #pragma unroll
        for (int k = 0; k < 8; ++k) {
            const int i = tid + 256 * (g * 8 + k);
            const int row = i >> 7, tq = i & 127;
            uint2 sv;
            sv.x = cvt_pk(v[k].x, v[k].y);
            sv.y = cvt_pk(v[k].z, v[k].w);
            const int pc = (tq >> 1) ^ (row & 7);          // swizzled 8-short chunk
            *(uint2*)(xs + row * XS_PITCH + pc * 8 + (tq & 1) * 4) = sv;
        }
    }
    __syncthreads();

    // ---- phase 1b: S partial + gram MFMA (K = 512 t-pad, zeros inert) ----
    {
        float s_acc = 0.f;
        const short* rowp = xs + lane * XS_PITCH;
        #pragma unroll
        for (int j = 0; j < 16; ++j) {
            const int pc = (wave * 16 + j) ^ (lane & 7);
            uint2 u0 = *(const uint2*)(rowp + pc * 8);
            uint2 u1 = *(const uint2*)(rowp + pc * 8 + 4);
            s_acc += bfpair(u0.x) + bfpair(u0.y) + bfpair(u1.x) + bfpair(u1.y);
        }
        f32x16 acc;
        #pragma unroll
        for (int z = 0; z < 16; ++z) acc[z] = 0.f;
        #pragma unroll
        for (int ks = 0; ks < 32; ++ks) {
            const int ck = ks * 2 + half;                  // logical chunk 0..63
            short8 av = *(const short8*)(xs + (r0 + m) * XS_PITCH + (ck ^ (m & 7)) * 8);
            short8 bv = *(const short8*)(xs + (c0w + m) * XS_PITCH + (ck ^ (m & 7)) * 8);
            acc = __builtin_amdgcn_mfma_f32_32x32x16_bf16(av, bv, acc, 0, 0, 0);
        }
        red[wave * 64 + lane] = s_acc;
        __syncthreads();
        if (tid < 64) {
            float s = red[tid] + red[64 + tid] + red[128 + tid] + red[192 + tid];
            S_part[(slab * BB + b) * CC + tid] = s;
        }
        float* gp = G_part + ((size_t)slab * BB + b) * (CC * CC);
        #pragma unroll
        for (int r = 0; r < 16; ++r) {
            const int row = (r & 3) + 8 * (r >> 2) + 4 * half;
            gp[(r0 + row) * CC + (c0w + m)] = acc[r];
        }
    }

    // ---- grid spin barrier (all 512 blocks co-resident; bounded: fails visibly,
    //      never hangs, if co-residency assumption breaks) ----
    __threadfence();
    __syncthreads();
    if (tid == 0) {
        __hip_atomic_fetch_add(bar, 1u, __ATOMIC_ACQ_REL, __HIP_MEMORY_SCOPE_AGENT);
        unsigned it = 0;
        while (__hip_atomic_load(bar, __ATOMIC_ACQUIRE, __HIP_MEMORY_SCOPE_AGENT) < NWG) {
            __builtin_amdgcn_s_sleep(2);
            if (++it > (1u << 26)) break;   // safety valve ~seconds
        }
    }
    __syncthreads();
    __threadfence();

    // ---- phase 2: softmax for batch b (redundant per block; G reads L2-local) ----
    {
        const int c = lane, q = wave;
        if (tid < 64) {
            float s = 0.f;
            #pragma unroll
            for (int sl = 0; sl < SLABS; ++sl)
                s += S_part[(sl * BB + b) * CC + tid];
            Sb[tid] = s;
        }
        float A = 0.f, Bc = 0.f, Be = 0.f, Cc = 0.f;
        #pragma unroll
        for (int j = 0; j < 8; ++j) {
            float a1 = w1[j], a2 = w2[j], q1 = b1[j], q2 = b2[j];
            A += a1 * a2; Bc += a1 * q2; Be += q1 * a2; Cc += q1 * q2;
        }
        Cc *= (float)TT;

        float g16[16];
        #pragma unroll
        for (int i = 0; i < 16; ++i) g16[i] = 0.f;
        const float* gb = G_part + (size_t)b * (CC * CC) + c * 64 + 16 * q;
        #pragma unroll
        for (int sl = 0; sl < SLABS; ++sl) {
            const float* p = gb + (size_t)sl * BB * (CC * CC);
            float4 v0 = *(const float4*)(p);
            float4 v1 = *(const float4*)(p + 4);
            float4 v2 = *(const float4*)(p + 8);
            float4 v3 = *(const float4*)(p + 12);
            g16[0]  += v0.x; g16[1]  += v0.y; g16[2]  += v0.z; g16[3]  += v0.w;
            g16[4]  += v1.x; g16[5]  += v1.y; g16[6]  += v1.z; g16[7]  += v1.w;
            g16[8]  += v2.x; g16[9]  += v2.y; g16[10] += v2.z; g16[11] += v2.w;
            g16[12] += v3.x; g16[13] += v3.y; g16[14] += v3.z; g16[15] += v3.w;
        }
        __syncthreads();   // Sb ready; red free from phase 1

        const float sc = Sb[c];
        float ev[16], mn = 1e30f, mx = -1e30f;
        #pragma unroll
        for (int i = 0; i < 16; ++i) {
            float en = A * g16[i] + Bc * sc + Be * Sb[16 * q + i] + Cc;
            ev[i] = en;
            mn = fminf(mn, en); mx = fmaxf(mx, en);
        }
        red[q * 64 + c] = mn; red[256 + q * 64 + c] = mx;
        __syncthreads();
        mn = fminf(fminf(red[c], red[64 + c]), fminf(red[128 + c], red[192 + c]));
        mx = fmaxf(fmaxf(red[256 + c], red[320 + c]), fmaxf(red[384 + c], red[448 + c]));
        const float ninv = 1.f / (mx - mn + 1e-8f);
        float pv[16], ls = 0.f;
        #pragma unroll
        for (int i = 0; i < 16; ++i) {
            float p = __expf((ev[i] - mn) * ninv);
            pv[i] = p; ls += p;
        }
        red[512 + q * 64 + c] = ls;
        __syncthreads();
        const float rinv = 1.f / (red[512 + c] + red[576 + c] + red[640 + c] + red[704 + c]);
        // al[e][c] = bf16(attention[c][e])
        #pragma unroll
        for (int i = 0; i < 16; ++i)
            al[(16 * q + i) * APITCH + c] = f2bf(pv[i] * rinv);
        __syncthreads();   // al ready; xs untouched since phase 1
    }

    // ---- phase 3: apply from the RESIDENT xs tile; barrier-free ----
    {
        short8 av[4];
        #pragma unroll
        for (int ks = 0; ks < 4; ++ks)
            av[ks] = *(const short8*)(al + (c0w + m) * APITCH + ks * 16 + 8 * half);

        const float gm = gamma[0];
        float* ob = out + (size_t)b * CC * TT;
        const int tb = (wave >> 1) * 64;

        #pragma unroll
        for (int it = 0; it < 4; ++it) {
            const int tl0 = it * 128 + tb + m;             // local t in [0,512)
            const int tl1 = tl0 + 32;
            const int cq0 = tl0 >> 3, cq1 = tl1 >> 3, el = tl0 & 7;
            f32x16 acc0, acc1;
            #pragma unroll
            for (int z = 0; z < 16; ++z) { acc0[z] = 0.f; acc1[z] = 0.f; }

            #pragma unroll
            for (int ks = 0; ks < 4; ++ks) {
                short8 bv0, bv1;
                #pragma unroll
                for (int j = 0; j < 8; ++j) {
                    const int e = ks * 16 + 8 * half + j;
                    const short* rp = xs + e * XS_PITCH;
                    bv0[j] = rp[((cq0 ^ (e & 7)) << 3) + el];
                    bv1[j] = rp[((cq1 ^ (e & 7)) << 3) + el];
                }
                acc0 = __builtin_amdgcn_mfma_f32_32x32x16_bf16(av[ks], bv0, acc0, 0, 0, 0);
                acc1 = __builtin_amdgcn_mfma_f32_32x32x16_bf16(av[ks], bv1, acc1, 0, 0, 0);
            }

            #pragma unroll
            for (int r = 0; r < 16; ++r) {
                const int row = (r & 3) + 8 * (r >> 2) + 4 * half;
                const int cc2 = c0w + row;
                const short* rp = xs + cc2 * XS_PITCH;
                if (tl0 < SLABT) {
                    const float res = bf2f(rp[((cq0 ^ (cc2 & 7)) << 3) + el]);
                    ob[cc2 * TT + t0s + tl0] = gm * acc0[r] + res;
                }
                if (tl1 < SLABT) {
                    const float res = bf2f(rp[((cq1 ^ (cc2 & 7)) << 3) + el]);
                    ob[cc2 * TT + t0s + tl1] = gm * acc1[r] + res;
                }
            }
        }
    }
}

extern "C" void kernel_launch(void* const* d_in, const int* in_sizes, int n_in,
                              void* d_out, int out_size, void* d_ws, size_t ws_size,
                              hipStream_t stream) {
    const float* x  = (const float*)d_in[0];
    const float* w1 = (const float*)d_in[1];
    const float* b1 = (const float*)d_in[2];
    const float* w2 = (const float*)d_in[3];
    const float* b2 = (const float*)d_in[4];
    const float* gm = (const float*)d_in[5];
    float* out = (float*)d_out;

    float* G_part = (float*)d_ws;
    float* S_part = G_part + GPART_ELEMS;
    unsigned* bar = (unsigned*)(S_part + SPART_ELEMS);

    // zero the barrier counter (ws is poisoned); async -> graph-capture safe
    hipMemsetAsync(bar, 0, sizeof(unsigned), stream);
    hipLaunchKernelGGL(fused_attn, dim3(NWG), dim3(256), 0, stream,
                       x, w1, b1, w2, b2, gm, G_part, S_part, bar, out);
}